// Round 1
// baseline (1803.578 us; speedup 1.0000x reference)
//
#include <hip/hip_runtime.h>
#include <hip/hip_bf16.h>
#include <math.h>

#define S_ 2048
#define D_ 1024
#define H_ 4
#define HD_ 256
#define B_ 4

typedef __hip_bfloat16 bf16;

__device__ __forceinline__ float tofloat(float x) { return x; }
__device__ __forceinline__ float tofloat(bf16 x) { return __bfloat162float(x); }

// ---------------------------------------------------------------------------
// Generic tiled GEMM:  C[m,n] = sum_k A[m,k] * B[n,k]   (NT form, row-major)
// 64x64 tile, BK=16, 256 threads, 4x4 register tile per thread.
// All of M, N, K are multiples of 64/16 in this problem -> no bounds checks.
// Batch via blockIdx.z decomposed as zb = z/zdiv, zh = z%zdiv.
// MODE: 0 = fp32 store, 1 = bf16 store, 2 = bf16 transposed store (C[n,m]),
//       3 = fp32 store + per-head attention bias (zh == head).
// ---------------------------------------------------------------------------
template <typename TA, typename TB, int MODE>
__global__ __launch_bounds__(256) void gemm_nt(
    int M, int N, int Kd,
    const TA* __restrict__ A, int lda, int zdiv, long sA_b, long sA_h,
    const TB* __restrict__ Bm, int ldb, long sB_b, long sB_h,
    void* __restrict__ Cp, int ldc, long sC_b, long sC_h,
    float alpha,
    int bbatch, const double* __restrict__ mag1d, const double* __restrict__ v3d,
    const double* __restrict__ meand, const float* __restrict__ bias_sc)
{
    __shared__ float As[16][68];  // +4 pad: keeps 16B alignment for float4 reads
    __shared__ float Bs[16][68];

    const int tid = threadIdx.x;
    const int zb = blockIdx.z / zdiv, zh = blockIdx.z % zdiv;
    const TA* Ap = A + zb * sA_b + zh * sA_h + (long)blockIdx.y * 64 * lda;
    const TB* Bp = Bm + zb * sB_b + zh * sB_h + (long)blockIdx.x * 64 * ldb;

    const int kk = tid & 15, mm = tid >> 4;   // global-load mapping
    const int tx = tid & 15, ty = tid >> 4;   // compute mapping

    float acc[4][4] = {};

    for (int k0 = 0; k0 < Kd; k0 += 16) {
#pragma unroll
        for (int i = 0; i < 4; i++) {
            As[kk][mm + 16 * i] = tofloat(Ap[(long)(mm + 16 * i) * lda + k0 + kk]);
            Bs[kk][mm + 16 * i] = tofloat(Bp[(long)(mm + 16 * i) * ldb + k0 + kk]);
        }
        __syncthreads();
#pragma unroll
        for (int k = 0; k < 16; k++) {
            float av[4], bv[4];
#pragma unroll
            for (int i = 0; i < 4; i++) av[i] = As[k][ty * 4 + i];
#pragma unroll
            for (int j = 0; j < 4; j++) bv[j] = Bs[k][tx * 4 + j];
#pragma unroll
            for (int i = 0; i < 4; i++)
#pragma unroll
                for (int j = 0; j < 4; j++) acc[i][j] += av[i] * bv[j];
        }
        __syncthreads();
    }

    const int row0 = blockIdx.y * 64 + ty * 4;
    const int col0 = blockIdx.x * 64 + tx * 4;

    if (MODE == 0) {
        float* C = (float*)Cp + zb * sC_b + zh * sC_h;
#pragma unroll
        for (int i = 0; i < 4; i++)
#pragma unroll
            for (int j = 0; j < 4; j++)
                C[(long)(row0 + i) * ldc + (col0 + j)] = acc[i][j] * alpha;
    } else if (MODE == 1) {
        bf16* C = (bf16*)Cp + zb * sC_b + zh * sC_h;
#pragma unroll
        for (int i = 0; i < 4; i++)
#pragma unroll
            for (int j = 0; j < 4; j++)
                C[(long)(row0 + i) * ldc + (col0 + j)] = __float2bfloat16(acc[i][j] * alpha);
    } else if (MODE == 2) {
        bf16* C = (bf16*)Cp + zb * sC_b + zh * sC_h;
#pragma unroll
        for (int i = 0; i < 4; i++)
#pragma unroll
            for (int j = 0; j < 4; j++)
                C[(long)(col0 + j) * ldc + (row0 + i)] = __float2bfloat16(acc[i][j] * alpha);
    } else {  // MODE == 3: scores + legal bias, zh = head index
        float* C = (float*)Cp + zb * sC_b + zh * sC_h;
        const int h = zh;
        const float bsc = bias_sc[h];
        const double mean = (h == 1) ? meand[0] : 0.0;
        double as_[4], at_[4];
        if (h == 1 || h == 3) {
            const double* src = (h == 1) ? mag1d : v3d;
#pragma unroll
            for (int i = 0; i < 4; i++) as_[i] = src[(long)bbatch * S_ + row0 + i];
#pragma unroll
            for (int j = 0; j < 4; j++) at_[j] = src[(long)bbatch * S_ + col0 + j];
        }
#pragma unroll
        for (int i = 0; i < 4; i++)
#pragma unroll
            for (int j = 0; j < 4; j++) {
                const int r = row0 + i, c = col0 + j;
                float bias;
                if (h == 0)      bias = (c > r) ? bsc : 0.0f;                       // causal triu(k=1)
                else if (h == 1) bias = (as_[i] * at_[j] > mean) ? bsc : 0.0f;      // intent
                else if (h == 2) bias = bsc * expf(-(float)abs(c - r) * (1.0f / 2048.0f)); // prox
                else             bias = (as_[i] * at_[j] > 0.5) ? bsc : 0.0f;       // violation
                C[(long)r * ldc + c] = acc[i][j] + bias;
            }
    }
}

// ---------------------------------------------------------------------------
// mag1[b,s] = ||emb[b,s,256:512]||  (head 1), v3[b,s] = emb[b,s,1023]  (fp64)
// ---------------------------------------------------------------------------
__global__ __launch_bounds__(256) void prep_kernel(const float* __restrict__ emb,
                                                   double* __restrict__ mag1d,
                                                   double* __restrict__ v3d) {
    const long row = blockIdx.x;  // b*S + s
    const int tid = threadIdx.x;
    const float x = emb[row * D_ + 256 + tid];
    __shared__ double red[256];
    red[tid] = (double)x * (double)x;
    __syncthreads();
    for (int off = 128; off > 0; off >>= 1) {
        if (tid < off) red[tid] += red[tid + off];
        __syncthreads();
    }
    if (tid == 0) {
        mag1d[row] = sqrt(red[0]);
        v3d[row] = (double)emb[row * D_ + 1023];
    }
}

// mean over (B,S,S) of mag1[b,s]*mag1[b,t] = (1/B) sum_b (sum_s mag1[b,s] / S)^2
__global__ __launch_bounds__(256) void mean_kernel(const double* __restrict__ mag1d,
                                                   double* __restrict__ meand) {
    const int tid = threadIdx.x;
    __shared__ double red[256];
    double acc = 0.0;
    for (int b = 0; b < B_; b++) {
        double ss = 0.0;
        for (int i = tid; i < S_; i += 256) ss += mag1d[(long)b * S_ + i];
        __syncthreads();
        red[tid] = ss;
        __syncthreads();
        for (int off = 128; off > 0; off >>= 1) {
            if (tid < off) red[tid] += red[tid + off];
            __syncthreads();
        }
        if (tid == 0) {
            const double rb = red[0] / (double)S_;
            acc += rb * rb;
        }
        __syncthreads();
    }
    if (tid == 0) meand[0] = acc / (double)B_;
}

// Row softmax in place over scores[h,s,:] (one b-batch buffer [H,S,S])
__global__ __launch_bounds__(256) void softmax_rows(float* __restrict__ scores) {
    const int s = blockIdx.x, h = blockIdx.y;
    float* row = scores + ((long)h * S_ + s) * S_;
    const int tid = threadIdx.x;
    __shared__ float red[256];
    float v[8];
    float m = -1e30f;
#pragma unroll
    for (int i = 0; i < 8; i++) {
        v[i] = row[tid + 256 * i];
        m = fmaxf(m, v[i]);
    }
    red[tid] = m;
    __syncthreads();
    for (int off = 128; off > 0; off >>= 1) {
        if (tid < off) red[tid] = fmaxf(red[tid], red[tid + off]);
        __syncthreads();
    }
    m = red[0];
    __syncthreads();
    float sum = 0.0f;
#pragma unroll
    for (int i = 0; i < 8; i++) {
        v[i] = expf(v[i] - m);
        sum += v[i];
    }
    red[tid] = sum;
    __syncthreads();
    for (int off = 128; off > 0; off >>= 1) {
        if (tid < off) red[tid] += red[tid + off];
        __syncthreads();
    }
    const float inv = 1.0f / red[0];
#pragma unroll
    for (int i = 0; i < 8; i++) row[tid + 256 * i] = v[i] * inv;
}

// avg over heads -> d_out avgw region; also row sums (for guilt)
__global__ __launch_bounds__(256) void avgw_kernel(const float* __restrict__ w,
                                                   float* __restrict__ avgw,
                                                   float* __restrict__ rowsum) {
    const int s = blockIdx.x, tid = threadIdx.x;
    const float* r0 = w + (long)s * S_;
    float acc = 0.0f;
    for (int t = tid; t < S_; t += 256) {
        const float v = 0.25f * (r0[t] + r0[t + (long)S_ * S_] + r0[t + 2L * S_ * S_] +
                                 r0[t + 3L * S_ * S_]);
        avgw[(long)s * S_ + t] = v;
        acc += v;
    }
    __shared__ float red[256];
    red[tid] = acc;
    __syncthreads();
    for (int off = 128; off > 0; off >>= 1) {
        if (tid < off) red[tid] += red[tid + off];
        __syncthreads();
    }
    if (tid == 0) rowsum[s] = red[0];
}

// y = proj + Wo_b + emb; LayerNorm(y) in place on d_out output region
__global__ __launch_bounds__(256) void ln_kernel(float* __restrict__ out,
                                                 const float* __restrict__ emb,
                                                 const float* __restrict__ wob,
                                                 const float* __restrict__ g,
                                                 const float* __restrict__ beta) {
    const long row = blockIdx.x;
    float* o = out + row * D_;
    const float* e = emb + row * D_;
    const int tid = threadIdx.x;
    __shared__ float red[256];
    float v[4];
    float sum = 0.0f;
#pragma unroll
    for (int i = 0; i < 4; i++) {
        const int c = tid + 256 * i;
        v[i] = o[c] + wob[c] + e[c];
        sum += v[i];
    }
    red[tid] = sum;
    __syncthreads();
    for (int off = 128; off > 0; off >>= 1) {
        if (tid < off) red[tid] += red[tid + off];
        __syncthreads();
    }
    const float mu = red[0] * (1.0f / 1024.0f);
    __syncthreads();
    float vs = 0.0f;
#pragma unroll
    for (int i = 0; i < 4; i++) {
        const float d = v[i] - mu;
        vs += d * d;
    }
    red[tid] = vs;
    __syncthreads();
    for (int off = 128; off > 0; off >>= 1) {
        if (tid < off) red[tid] += red[tid + off];
        __syncthreads();
    }
    const float var = red[0] * (1.0f / 1024.0f);
    const float inv = 1.0f / sqrtf(var + 1e-5f);
#pragma unroll
    for (int i = 0; i < 4; i++) {
        const int c = tid + 256 * i;
        o[c] = (v[i] - mu) * inv * g[c] + beta[c];
    }
}

// guilt[b,:] = softmax(rowsum[b,:])
__global__ __launch_bounds__(256) void guilt_kernel(const float* __restrict__ rowsum,
                                                    float* __restrict__ guilt) {
    const int b = blockIdx.x, tid = threadIdx.x;
    const float* r = rowsum + (long)b * S_;
    float* gq = guilt + (long)b * S_;
    __shared__ float red[256];
    float v[8];
    float m = -1e30f;
#pragma unroll
    for (int i = 0; i < 8; i++) {
        v[i] = r[tid + 256 * i];
        m = fmaxf(m, v[i]);
    }
    red[tid] = m;
    __syncthreads();
    for (int off = 128; off > 0; off >>= 1) {
        if (tid < off) red[tid] = fmaxf(red[tid], red[tid + off]);
        __syncthreads();
    }
    m = red[0];
    __syncthreads();
    float sum = 0.0f;
#pragma unroll
    for (int i = 0; i < 8; i++) {
        v[i] = expf(v[i] - m);
        sum += v[i];
    }
    red[tid] = sum;
    __syncthreads();
    for (int off = 128; off > 0; off >>= 1) {
        if (tid < off) red[tid] += red[tid + off];
        __syncthreads();
    }
    const float inv = 1.0f / red[0];
#pragma unroll
    for (int i = 0; i < 8; i++) gq[tid + 256 * i] = v[i] * inv;
}

extern "C" void kernel_launch(void* const* d_in, const int* in_sizes, int n_in,
                              void* d_out, int out_size, void* d_ws, size_t ws_size,
                              hipStream_t stream) {
    const float* emb = (const float*)d_in[0];
    const float* Wq = (const float*)d_in[1];
    const float* Wk = (const float*)d_in[2];
    const float* Wv = (const float*)d_in[3];
    const float* bias_sc = (const float*)d_in[4];
    const float* Wo_w = (const float*)d_in[5];
    const float* Wo_b = (const float*)d_in[6];
    const float* ln_g = (const float*)d_in[7];
    const float* ln_bt = (const float*)d_in[8];

    // workspace layout (bytes), 256-aligned
    char* ws = (char*)d_ws;
    size_t off = 0;
    auto alloc = [&](size_t bytes) {
        size_t o = off;
        off = (off + bytes + 255) & ~(size_t)255;
        return o;
    };
    const size_t qkv_b = (size_t)B_ * H_ * S_ * HD_ * sizeof(bf16);  // 16.78 MB each
    bf16* Qb = (bf16*)(ws + alloc(qkv_b));
    bf16* Kb = (bf16*)(ws + alloc(qkv_b));
    bf16* Vtb = (bf16*)(ws + alloc(qkv_b));                          // [B,H,hd,S]
    float* scores = (float*)(ws + alloc((size_t)H_ * S_ * S_ * 4));  // per-b [H,S,S], 67 MB
    bf16* concat = (bf16*)(ws + alloc((size_t)B_ * S_ * D_ * sizeof(bf16)));
    double* mag1d = (double*)(ws + alloc((size_t)B_ * S_ * 8));
    double* v3d = (double*)(ws + alloc((size_t)B_ * S_ * 8));
    double* meand = (double*)(ws + alloc(256));
    float* rowsum = (float*)(ws + alloc((size_t)B_ * S_ * 4));
    (void)ws_size;

    float* outp = (float*)d_out;                       // [B,S,D]
    float* avgw = outp + (size_t)B_ * S_ * D_;         // [B,S,S]
    float* guilt = avgw + (size_t)B_ * S_ * S_;        // [B,S]

    prep_kernel<<<B_ * S_, 256, 0, stream>>>(emb, mag1d, v3d);
    mean_kernel<<<1, 256, 0, stream>>>(mag1d, meand);

    // Q,K,V projections: per (b,h): x[b,h] (S x hd, lda=D) . W[h]^T -> [S,hd]
    {
        dim3 g(HD_ / 64, S_ / 64, B_ * H_);
        // Q (scaled by 1/sqrt(hd) = 1/16, folded in)
        gemm_nt<float, float, 1><<<g, 256, 0, stream>>>(
            S_, HD_, HD_, emb, D_, H_, (long)S_ * D_, 256,
            Wq, HD_, 0, (long)HD_ * HD_,
            Qb, HD_, (long)H_ * S_ * HD_, (long)S_ * HD_,
            0.0625f, 0, nullptr, nullptr, nullptr, nullptr);
        gemm_nt<float, float, 1><<<g, 256, 0, stream>>>(
            S_, HD_, HD_, emb, D_, H_, (long)S_ * D_, 256,
            Wk, HD_, 0, (long)HD_ * HD_,
            Kb, HD_, (long)H_ * S_ * HD_, (long)S_ * HD_,
            1.0f, 0, nullptr, nullptr, nullptr, nullptr);
        // V stored transposed: Vt[b,h,e,s]
        gemm_nt<float, float, 2><<<g, 256, 0, stream>>>(
            S_, HD_, HD_, emb, D_, H_, (long)S_ * D_, 256,
            Wv, HD_, 0, (long)HD_ * HD_,
            Vtb, S_, (long)H_ * HD_ * S_, (long)HD_ * S_,
            1.0f, 0, nullptr, nullptr, nullptr, nullptr);
    }

    for (int b = 0; b < B_; b++) {
        // scores[h,s,t] = (Q/16).K + bias(h,b,s,t)
        gemm_nt<bf16, bf16, 3><<<dim3(S_ / 64, S_ / 64, H_), 256, 0, stream>>>(
            S_, S_, HD_,
            Qb + (long)b * H_ * S_ * HD_, HD_, H_, 0, (long)S_ * HD_,
            Kb + (long)b * H_ * S_ * HD_, HD_, 0, (long)S_ * HD_,
            scores, S_, 0, (long)S_ * S_,
            1.0f, b, mag1d, v3d, meand, bias_sc);
        softmax_rows<<<dim3(S_, H_), 256, 0, stream>>>(scores);
        avgw_kernel<<<S_, 256, 0, stream>>>(scores, avgw + (long)b * S_ * S_,
                                            rowsum + (long)b * S_);
        // attended[s,e] = w[s,:].Vt[e,:] -> concat[b,s,h*256+e]  (bf16)
        gemm_nt<float, bf16, 1><<<dim3(HD_ / 64, S_ / 64, H_), 256, 0, stream>>>(
            S_, HD_, S_,
            scores, S_, H_, 0, (long)S_ * S_,
            Vtb + (long)b * H_ * HD_ * S_, S_, 0, (long)HD_ * S_,
            concat + (long)b * S_ * D_, D_, 0, 256,
            1.0f, 0, nullptr, nullptr, nullptr, nullptr);
    }

    // out = concat @ Wo_w^T  (bias/residual/LN fused in ln_kernel)
    gemm_nt<bf16, float, 0><<<dim3(D_ / 64, (B_ * S_) / 64, 1), 256, 0, stream>>>(
        B_ * S_, D_, D_,
        concat, D_, 1, 0, 0,
        Wo_w, D_, 0, 0,
        outp, D_, 0, 0,
        1.0f, 0, nullptr, nullptr, nullptr, nullptr);

    ln_kernel<<<B_ * S_, 256, 0, stream>>>(outp, emb, Wo_b, ln_g, ln_bt);
    guilt_kernel<<<B_, 256, 0, stream>>>(rowsum, guilt);
}

// Round 2
// 741.586 us; speedup vs baseline: 2.4321x; 2.4321x over previous
//
#include <hip/hip_runtime.h>
#include <hip/hip_bf16.h>
#include <math.h>

#define S_ 2048
#define D_ 1024
#define H_ 4
#define HD_ 256
#define B_ 4

typedef __hip_bfloat16 bf16;
typedef short s16x8 __attribute__((ext_vector_type(8)));
typedef float f32x4 __attribute__((ext_vector_type(4)));

__device__ __forceinline__ float tofloat(float x) { return x; }
__device__ __forceinline__ float tofloat(bf16 x) { return __bfloat162float(x); }

// async global->LDS, 16B per lane; LDS dest is wave-uniform base + lane*16
#define GLOAD16(g, l)                                             \
    __builtin_amdgcn_global_load_lds(                             \
        (const __attribute__((address_space(1))) void*)(g),       \
        (__attribute__((address_space(3))) void*)(l), 16, 0, 0)

// ---------------------------------------------------------------------------
// MFMA NT GEMM: C[m,n] = sum_k A[m,k]*B[n,k], A/B bf16 row-major.
// 128x128 tile, BK=32, 256 threads = 4 waves (2x2), each wave 4x4 frags of
// 16x16x32 bf16 MFMA. M,N mult of 128; K mult of 32 (true for all uses).
// MODE: 0 = fp32 store, 1 = bf16 store, 3 = fp32 store + legal-bias (z=head).
// ---------------------------------------------------------------------------
template <int MODE>
__global__ __launch_bounds__(256) void mfma_nt(
    int K,
    const bf16* __restrict__ A, int lda, long sA_z,
    const bf16* __restrict__ Bm, int ldb, long sB_z,
    void* __restrict__ Cp, int ldc, long sC_z,
    int bbatch, const double* __restrict__ mag1d, const double* __restrict__ v3d,
    const double* __restrict__ meand, const float* __restrict__ bias_sc)
{
    __shared__ __align__(16) short As[128 * 32];
    __shared__ __align__(16) short Bs[128 * 32];

    const int tid = threadIdx.x;
    const int w = tid >> 6, lane = tid & 63;
    const int srow = lane >> 2, scol = (lane & 3) << 3;  // staging: 16 rows/inst
    const int quad = lane >> 4, r = lane & 15;           // mfma fragment coords
    const int wr = (w >> 1) * 64, wc = (w & 1) * 64;     // wave's 64x64 quadrant
    const int z = blockIdx.z;

    const bf16* Ap = A + (size_t)z * sA_z + (size_t)blockIdx.y * 128 * lda;
    const bf16* Bp = Bm + (size_t)z * sB_z + (size_t)blockIdx.x * 128 * ldb;

    f32x4 acc[4][4] = {};

    for (int k0 = 0; k0 < K; k0 += 32) {
        if (k0) __syncthreads();  // previous compute done before LDS overwrite
#pragma unroll
        for (int l = 0; l < 2; l++) {
            // wave w stages rows [w*32+l*16, +16) of each 128x32 tile
            GLOAD16(Ap + (size_t)(w * 32 + l * 16 + srow) * lda + (k0 + scol),
                    &As[(w * 32 + l * 16) * 32]);
            GLOAD16(Bp + (size_t)(w * 32 + l * 16 + srow) * ldb + (k0 + scol),
                    &Bs[(w * 32 + l * 16) * 32]);
        }
        __syncthreads();  // drains vmcnt (compiler emits waitcnt before barrier)

        s16x8 af[4], bfv[4];
        const s16x8* A8 = (const s16x8*)As;
        const s16x8* B8 = (const s16x8*)Bs;
#pragma unroll
        for (int i = 0; i < 4; i++) af[i] = A8[(wr + i * 16 + r) * 4 + quad];
#pragma unroll
        for (int j = 0; j < 4; j++) bfv[j] = B8[(wc + j * 16 + r) * 4 + quad];
#pragma unroll
        for (int i = 0; i < 4; i++)
#pragma unroll
            for (int j = 0; j < 4; j++)
                acc[i][j] = __builtin_amdgcn_mfma_f32_16x16x32_bf16(
                    af[i], bfv[j], acc[i][j], 0, 0, 0);
    }

    // C/D layout: col = lane&15, row = quad*4 + reg   [m89-verified]
    const int row0 = blockIdx.y * 128 + wr + quad * 4;
    const int col0 = blockIdx.x * 128 + wc + r;

    if (MODE == 0) {
        float* C = (float*)Cp + (size_t)z * sC_z;
#pragma unroll
        for (int i = 0; i < 4; i++)
#pragma unroll
            for (int j = 0; j < 4; j++)
#pragma unroll
                for (int p = 0; p < 4; p++)
                    C[(size_t)(row0 + i * 16 + p) * ldc + (col0 + j * 16)] = acc[i][j][p];
    } else if (MODE == 1) {
        bf16* C = (bf16*)Cp + (size_t)z * sC_z;
#pragma unroll
        for (int i = 0; i < 4; i++)
#pragma unroll
            for (int j = 0; j < 4; j++)
#pragma unroll
                for (int p = 0; p < 4; p++)
                    C[(size_t)(row0 + i * 16 + p) * ldc + (col0 + j * 16)] =
                        __float2bfloat16(acc[i][j][p]);
    } else {  // MODE 3: scores + legal bias; z = head
        float* C = (float*)Cp + (size_t)z * sC_z;
        const int h = z;
        const float bsc = bias_sc[h];
        if (h == 0) {  // causal triu(k=1)
#pragma unroll
            for (int i = 0; i < 4; i++)
#pragma unroll
                for (int j = 0; j < 4; j++)
#pragma unroll
                    for (int p = 0; p < 4; p++) {
                        const int rr = row0 + i * 16 + p, c = col0 + j * 16;
                        C[(size_t)rr * ldc + c] = acc[i][j][p] + ((c > rr) ? bsc : 0.0f);
                    }
        } else if (h == 2) {  // proximity
#pragma unroll
            for (int i = 0; i < 4; i++)
#pragma unroll
                for (int j = 0; j < 4; j++)
#pragma unroll
                    for (int p = 0; p < 4; p++) {
                        const int rr = row0 + i * 16 + p, c = col0 + j * 16;
                        int d = c - rr; d = d < 0 ? -d : d;
                        C[(size_t)rr * ldc + c] =
                            acc[i][j][p] + bsc * expf(-(float)d * (1.0f / 2048.0f));
                    }
        } else {  // h==1 intent (> mean) / h==3 violation (> 0.5), exact fp64 compare
            const double* src = (h == 1) ? mag1d : v3d;
            const double thr = (h == 1) ? meand[0] : 0.5;
            double rv[16], cv[4];
#pragma unroll
            for (int i = 0; i < 4; i++)
#pragma unroll
                for (int p = 0; p < 4; p++)
                    rv[i * 4 + p] = src[(size_t)bbatch * S_ + row0 + i * 16 + p];
#pragma unroll
            for (int j = 0; j < 4; j++)
                cv[j] = src[(size_t)bbatch * S_ + col0 + j * 16];
#pragma unroll
            for (int i = 0; i < 4; i++)
#pragma unroll
                for (int j = 0; j < 4; j++)
#pragma unroll
                    for (int p = 0; p < 4; p++) {
                        const int rr = row0 + i * 16 + p, c = col0 + j * 16;
                        C[(size_t)rr * ldc + c] =
                            acc[i][j][p] + ((rv[i * 4 + p] * cv[j] > thr) ? bsc : 0.0f);
                    }
        }
    }
}

// ---------------------------------------------------------------------------
// fp32 vector NT GEMM for QKV projections (unchanged numerics from R1).
// MODE: 1 = bf16 store, 2 = bf16 transposed store.
// ---------------------------------------------------------------------------
template <int MODE>
__global__ __launch_bounds__(256) void gemm_nt_v(
    const float* __restrict__ A, int lda, long sA_b, long sA_h,
    const float* __restrict__ Bm, int ldb, long sB_h,
    bf16* __restrict__ Cp, int ldc, long sC_b, long sC_h,
    float alpha)
{
    __shared__ float Asm[16][68];
    __shared__ float Bsm[16][68];
    const int tid = threadIdx.x;
    const int zb = blockIdx.z / H_, zh = blockIdx.z % H_;
    const float* Ap = A + zb * sA_b + zh * sA_h + (long)blockIdx.y * 64 * lda;
    const float* Bp = Bm + zh * sB_h + (long)blockIdx.x * 64 * ldb;
    const int kk = tid & 15, mm = tid >> 4;
    const int tx = tid & 15, ty = tid >> 4;
    float acc[4][4] = {};
    for (int k0 = 0; k0 < HD_; k0 += 16) {
#pragma unroll
        for (int i = 0; i < 4; i++) {
            Asm[kk][mm + 16 * i] = Ap[(long)(mm + 16 * i) * lda + k0 + kk];
            Bsm[kk][mm + 16 * i] = Bp[(long)(mm + 16 * i) * ldb + k0 + kk];
        }
        __syncthreads();
#pragma unroll
        for (int k = 0; k < 16; k++) {
            float av[4], bv[4];
#pragma unroll
            for (int i = 0; i < 4; i++) av[i] = Asm[k][ty * 4 + i];
#pragma unroll
            for (int j = 0; j < 4; j++) bv[j] = Bsm[k][tx * 4 + j];
#pragma unroll
            for (int i = 0; i < 4; i++)
#pragma unroll
                for (int j = 0; j < 4; j++) acc[i][j] += av[i] * bv[j];
        }
        __syncthreads();
    }
    const int row0 = blockIdx.y * 64 + ty * 4;
    const int col0 = blockIdx.x * 64 + tx * 4;
    bf16* C = Cp + zb * sC_b + zh * sC_h;
#pragma unroll
    for (int i = 0; i < 4; i++)
#pragma unroll
        for (int j = 0; j < 4; j++) {
            const float v = acc[i][j] * alpha;
            if (MODE == 1)
                C[(long)(row0 + i) * ldc + (col0 + j)] = __float2bfloat16(v);
            else
                C[(long)(col0 + j) * ldc + (row0 + i)] = __float2bfloat16(v);
        }
}

__global__ __launch_bounds__(256) void f32_to_bf16(const float* __restrict__ in,
                                                   bf16* __restrict__ out, int n) {
    const int i0 = (blockIdx.x * 256 + threadIdx.x) * 4;
    if (i0 + 3 < n) {
#pragma unroll
        for (int i = 0; i < 4; i++) out[i0 + i] = __float2bfloat16(in[i0 + i]);
    }
}

// mag1[b,s] = ||emb[b,s,256:512]|| (fp64), v3[b,s] = emb[b,s,1023]
__global__ __launch_bounds__(256) void prep_kernel(const float* __restrict__ emb,
                                                   double* __restrict__ mag1d,
                                                   double* __restrict__ v3d) {
    const long row = blockIdx.x;
    const int tid = threadIdx.x;
    const float x = emb[row * D_ + 256 + tid];
    __shared__ double red[256];
    red[tid] = (double)x * (double)x;
    __syncthreads();
    for (int off = 128; off > 0; off >>= 1) {
        if (tid < off) red[tid] += red[tid + off];
        __syncthreads();
    }
    if (tid == 0) {
        mag1d[row] = sqrt(red[0]);
        v3d[row] = (double)emb[row * D_ + 1023];
    }
}

__global__ __launch_bounds__(256) void mean_kernel(const double* __restrict__ mag1d,
                                                   double* __restrict__ meand) {
    const int tid = threadIdx.x;
    __shared__ double red[256];
    double acc = 0.0;
    for (int b = 0; b < B_; b++) {
        double ss = 0.0;
        for (int i = tid; i < S_; i += 256) ss += mag1d[(long)b * S_ + i];
        __syncthreads();
        red[tid] = ss;
        __syncthreads();
        for (int off = 128; off > 0; off >>= 1) {
            if (tid < off) red[tid] += red[tid + off];
            __syncthreads();
        }
        if (tid == 0) {
            const double rb = red[0] / (double)S_;
            acc += rb * rb;
        }
        __syncthreads();
    }
    if (tid == 0) meand[0] = acc / (double)B_;
}

// Fused: per row s, for all 4 heads: softmax (fp32, same op order as R1),
// write P as bf16 IN PLACE over the fp32 row (first half), accumulate
// head-average -> avgw (fp32) and row sum -> rowsum.
__global__ __launch_bounds__(256) void softmax_fused(float* __restrict__ scores,
                                                     float* __restrict__ avgw,
                                                     float* __restrict__ rowsum) {
    const int s = blockIdx.x, tid = threadIdx.x;
    __shared__ float red[256];
    float wacc[8] = {0, 0, 0, 0, 0, 0, 0, 0};
    for (int h = 0; h < H_; h++) {
        float* rp = scores + ((size_t)h * S_ + s) * S_;
        bf16* pp = (bf16*)rp;  // alias: bf16 P overwrites this row's own storage
        float v[8];
        float m = -1e30f;
#pragma unroll
        for (int i = 0; i < 8; i++) {
            v[i] = rp[tid + 256 * i];
            m = fmaxf(m, v[i]);
        }
        red[tid] = m;
        __syncthreads();
        for (int off = 128; off > 0; off >>= 1) {
            if (tid < off) red[tid] = fmaxf(red[tid], red[tid + off]);
            __syncthreads();
        }
        m = red[0];
        __syncthreads();
        float sum = 0.0f;
#pragma unroll
        for (int i = 0; i < 8; i++) {
            v[i] = expf(v[i] - m);
            sum += v[i];
        }
        red[tid] = sum;
        __syncthreads();
        for (int off = 128; off > 0; off >>= 1) {
            if (tid < off) red[tid] += red[tid + off];
            __syncthreads();
        }
        const float inv = 1.0f / red[0];
        __syncthreads();
#pragma unroll
        for (int i = 0; i < 8; i++) {
            const float wv = v[i] * inv;
            pp[tid + 256 * i] = __float2bfloat16(wv);
            wacc[i] += wv;
        }
    }
    float asum = 0.0f;
#pragma unroll
    for (int i = 0; i < 8; i++) {
        const float a = wacc[i] * 0.25f;
        avgw[(size_t)s * S_ + tid + 256 * i] = a;
        asum += a;
    }
    red[tid] = asum;
    __syncthreads();
    for (int off = 128; off > 0; off >>= 1) {
        if (tid < off) red[tid] += red[tid + off];
        __syncthreads();
    }
    if (tid == 0) rowsum[s] = red[0];
}

// y = proj + Wo_b + emb; LayerNorm(y) in place
__global__ __launch_bounds__(256) void ln_kernel(float* __restrict__ out,
                                                 const float* __restrict__ emb,
                                                 const float* __restrict__ wob,
                                                 const float* __restrict__ g,
                                                 const float* __restrict__ beta) {
    const long row = blockIdx.x;
    float* o = out + row * D_;
    const float* e = emb + row * D_;
    const int tid = threadIdx.x;
    __shared__ float red[256];
    float v[4];
    float sum = 0.0f;
#pragma unroll
    for (int i = 0; i < 4; i++) {
        const int c = tid + 256 * i;
        v[i] = o[c] + wob[c] + e[c];
        sum += v[i];
    }
    red[tid] = sum;
    __syncthreads();
    for (int off = 128; off > 0; off >>= 1) {
        if (tid < off) red[tid] += red[tid + off];
        __syncthreads();
    }
    const float mu = red[0] * (1.0f / 1024.0f);
    __syncthreads();
    float vs = 0.0f;
#pragma unroll
    for (int i = 0; i < 4; i++) {
        const float d = v[i] - mu;
        vs += d * d;
    }
    red[tid] = vs;
    __syncthreads();
    for (int off = 128; off > 0; off >>= 1) {
        if (tid < off) red[tid] += red[tid + off];
        __syncthreads();
    }
    const float var = red[0] * (1.0f / 1024.0f);
    const float inv = 1.0f / sqrtf(var + 1e-5f);
#pragma unroll
    for (int i = 0; i < 4; i++) {
        const int c = tid + 256 * i;
        o[c] = (v[i] - mu) * inv * g[c] + beta[c];
    }
}

__global__ __launch_bounds__(256) void guilt_kernel(const float* __restrict__ rowsum,
                                                    float* __restrict__ guilt) {
    const int b = blockIdx.x, tid = threadIdx.x;
    const float* r = rowsum + (long)b * S_;
    float* gq = guilt + (long)b * S_;
    __shared__ float red[256];
    float v[8];
    float m = -1e30f;
#pragma unroll
    for (int i = 0; i < 8; i++) {
        v[i] = r[tid + 256 * i];
        m = fmaxf(m, v[i]);
    }
    red[tid] = m;
    __syncthreads();
    for (int off = 128; off > 0; off >>= 1) {
        if (tid < off) red[tid] = fmaxf(red[tid], red[tid + off]);
        __syncthreads();
    }
    m = red[0];
    __syncthreads();
    float sum = 0.0f;
#pragma unroll
    for (int i = 0; i < 8; i++) {
        v[i] = expf(v[i] - m);
        sum += v[i];
    }
    red[tid] = sum;
    __syncthreads();
    for (int off = 128; off > 0; off >>= 1) {
        if (tid < off) red[tid] += red[tid + off];
        __syncthreads();
    }
    const float inv = 1.0f / red[0];
#pragma unroll
    for (int i = 0; i < 8; i++) gq[tid + 256 * i] = v[i] * inv;
}

extern "C" void kernel_launch(void* const* d_in, const int* in_sizes, int n_in,
                              void* d_out, int out_size, void* d_ws, size_t ws_size,
                              hipStream_t stream) {
    const float* emb = (const float*)d_in[0];
    const float* Wq = (const float*)d_in[1];
    const float* Wk = (const float*)d_in[2];
    const float* Wv = (const float*)d_in[3];
    const float* bias_sc = (const float*)d_in[4];
    const float* Wo_w = (const float*)d_in[5];
    const float* Wo_b = (const float*)d_in[6];
    const float* ln_g = (const float*)d_in[7];
    const float* ln_bt = (const float*)d_in[8];

    char* ws = (char*)d_ws;
    size_t off = 0;
    auto alloc = [&](size_t bytes) {
        size_t o = off;
        off = (off + bytes + 255) & ~(size_t)255;
        return o;
    };
    const size_t qkv_b = (size_t)B_ * H_ * S_ * HD_ * sizeof(bf16);
    bf16* Qb = (bf16*)(ws + alloc(qkv_b));
    bf16* Kb = (bf16*)(ws + alloc(qkv_b));
    bf16* Vtb = (bf16*)(ws + alloc(qkv_b));                          // [B,H,hd,S]
    float* scores = (float*)(ws + alloc((size_t)H_ * S_ * S_ * 4));  // per-b [H,S,S]
    bf16* concat = (bf16*)(ws + alloc((size_t)B_ * S_ * D_ * sizeof(bf16)));
    bf16* Wob = (bf16*)(ws + alloc((size_t)D_ * D_ * sizeof(bf16)));
    double* mag1d = (double*)(ws + alloc((size_t)B_ * S_ * 8));
    double* v3d = (double*)(ws + alloc((size_t)B_ * S_ * 8));
    double* meand = (double*)(ws + alloc(256));
    float* rowsum = (float*)(ws + alloc((size_t)B_ * S_ * 4));
    (void)ws_size;

    float* outp = (float*)d_out;
    float* avgw = outp + (size_t)B_ * S_ * D_;
    float* guilt = avgw + (size_t)B_ * S_ * S_;

    prep_kernel<<<B_ * S_, 256, 0, stream>>>(emb, mag1d, v3d);
    mean_kernel<<<1, 256, 0, stream>>>(mag1d, meand);
    f32_to_bf16<<<(D_ * D_) / 1024, 256, 0, stream>>>(Wo_w, Wob, D_ * D_);

    // QKV projections (fp32 vector GEMM, numerics unchanged from R1)
    {
        dim3 g(HD_ / 64, S_ / 64, B_ * H_);
        gemm_nt_v<1><<<g, 256, 0, stream>>>(emb, D_, (long)S_ * D_, 256, Wq, HD_,
                                            (long)HD_ * HD_, Qb, HD_,
                                            (long)H_ * S_ * HD_, (long)S_ * HD_, 0.0625f);
        gemm_nt_v<1><<<g, 256, 0, stream>>>(emb, D_, (long)S_ * D_, 256, Wk, HD_,
                                            (long)HD_ * HD_, Kb, HD_,
                                            (long)H_ * S_ * HD_, (long)S_ * HD_, 1.0f);
        gemm_nt_v<2><<<g, 256, 0, stream>>>(emb, D_, (long)S_ * D_, 256, Wv, HD_,
                                            (long)HD_ * HD_, Vtb, S_,
                                            (long)H_ * HD_ * S_, (long)HD_ * S_, 1.0f);
    }

    for (int b = 0; b < B_; b++) {
        // scores[h,s,t] = Q.K^T + bias   (MFMA, bias epilogue, fp32 out)
        mfma_nt<3><<<dim3(16, 16, H_), 256, 0, stream>>>(
            HD_,
            Qb + (size_t)b * H_ * S_ * HD_, HD_, (long)S_ * HD_,
            Kb + (size_t)b * H_ * S_ * HD_, HD_, (long)S_ * HD_,
            scores, S_, (long)S_ * S_,
            b, mag1d, v3d, meand, bias_sc);
        // softmax + avgw + rowsum + in-place bf16 P
        softmax_fused<<<S_, 256, 0, stream>>>(scores, avgw + (size_t)b * S_ * S_,
                                              rowsum + (size_t)b * S_);
        // attended = P.V  (A = bf16 P aliased over scores rows, lda = 2S)
        mfma_nt<1><<<dim3(2, 16, H_), 256, 0, stream>>>(
            S_,
            (const bf16*)scores, 2 * S_, 2L * S_ * S_,
            Vtb + (size_t)b * H_ * HD_ * S_, S_, (long)HD_ * S_,
            concat + (size_t)b * S_ * D_, D_, 256,
            0, nullptr, nullptr, nullptr, nullptr);
    }

    // out = concat @ Wo^T (MFMA, bf16 Wo)
    mfma_nt<0><<<dim3(D_ / 128, (B_ * S_) / 128, 1), 256, 0, stream>>>(
        D_, concat, D_, 0, Wob, D_, 0, outp, D_, 0,
        0, nullptr, nullptr, nullptr, nullptr);

    ln_kernel<<<B_ * S_, 256, 0, stream>>>(outp, emb, Wo_b, ln_g, ln_bt);
    guilt_kernel<<<B_, 256, 0, stream>>>(rowsum, guilt);
}

// Round 3
// 522.948 us; speedup vs baseline: 3.4489x; 1.4181x over previous
//
#include <hip/hip_runtime.h>
#include <hip/hip_bf16.h>
#include <math.h>

#define S_ 2048
#define D_ 1024
#define H_ 4
#define HD_ 256
#define B_ 4

typedef __hip_bfloat16 bf16;
typedef short s16x8 __attribute__((ext_vector_type(8)));
typedef float f32x4 __attribute__((ext_vector_type(4)));

// async global->LDS, 16B per lane; LDS dest is wave-uniform base + lane*16
#define GLOAD16(g, l)                                             \
    __builtin_amdgcn_global_load_lds(                             \
        (const __attribute__((address_space(1))) void*)(g),       \
        (__attribute__((address_space(3))) void*)(l), 16, 0, 0)

// ---------------------------------------------------------------------------
// MFMA NT GEMM: C[m,n] = sum_k A[m,k]*B[n,k], A/B bf16 row-major.
// 128x128 tile, BK=32, 256 threads = 4 waves (2x2), each wave 4x4 frags of
// 16x16x32 bf16 MFMA. M,N multiples of 128; K multiple of 32.
// z decomposed: zb = z/zdiv, zh = z%zdiv; per-operand (b,h) strides in elems.
// MODE: 0 = fp32 store, 1 = bf16 store, 3 = fp32 store + legal-bias (h=zh,
//       bias batch = bbase + zb).
// ---------------------------------------------------------------------------
template <int MODE>
__global__ __launch_bounds__(256) void mfma_nt(
    int K,
    const bf16* __restrict__ A, int lda, long sA_b, long sA_h,
    const bf16* __restrict__ Bm, int ldb, long sB_b, long sB_h,
    void* __restrict__ Cp, int ldc, long sC_b, long sC_h,
    int zdiv, int bbase,
    const double* __restrict__ mag1d, const double* __restrict__ v3d,
    const double* __restrict__ meand, const float* __restrict__ bias_sc)
{
    __shared__ __align__(16) short As[128 * 32];
    __shared__ __align__(16) short Bs[128 * 32];

    const int tid = threadIdx.x;
    const int w = tid >> 6, lane = tid & 63;
    const int srow = lane >> 2, scol = (lane & 3) << 3;  // staging: 16 rows/inst
    const int quad = lane >> 4, r = lane & 15;           // mfma fragment coords
    const int wr = (w >> 1) * 64, wc = (w & 1) * 64;     // wave's 64x64 quadrant
    const int zb = blockIdx.z / zdiv, zh = blockIdx.z % zdiv;

    const bf16* Ap = A + (size_t)zb * sA_b + (size_t)zh * sA_h +
                     (size_t)blockIdx.y * 128 * lda;
    const bf16* Bp = Bm + (size_t)zb * sB_b + (size_t)zh * sB_h +
                     (size_t)blockIdx.x * 128 * ldb;

    f32x4 acc[4][4] = {};

    for (int k0 = 0; k0 < K; k0 += 32) {
        if (k0) __syncthreads();  // previous compute done before LDS overwrite
#pragma unroll
        for (int l = 0; l < 2; l++) {
            GLOAD16(Ap + (size_t)(w * 32 + l * 16 + srow) * lda + (k0 + scol),
                    &As[(w * 32 + l * 16) * 32]);
            GLOAD16(Bp + (size_t)(w * 32 + l * 16 + srow) * ldb + (k0 + scol),
                    &Bs[(w * 32 + l * 16) * 32]);
        }
        __syncthreads();  // drains vmcnt (compiler emits waitcnt before barrier)

        s16x8 af[4], bfv[4];
        const s16x8* A8 = (const s16x8*)As;
        const s16x8* B8 = (const s16x8*)Bs;
#pragma unroll
        for (int i = 0; i < 4; i++) af[i] = A8[(wr + i * 16 + r) * 4 + quad];
#pragma unroll
        for (int j = 0; j < 4; j++) bfv[j] = B8[(wc + j * 16 + r) * 4 + quad];
#pragma unroll
        for (int i = 0; i < 4; i++)
#pragma unroll
            for (int j = 0; j < 4; j++)
                acc[i][j] = __builtin_amdgcn_mfma_f32_16x16x32_bf16(
                    af[i], bfv[j], acc[i][j], 0, 0, 0);
    }

    // C/D layout: col = lane&15, row = quad*4 + reg   [m89-verified]
    const int row0 = blockIdx.y * 128 + wr + quad * 4;
    const int col0 = blockIdx.x * 128 + wc + r;

    if (MODE == 0) {
        float* C = (float*)Cp + (size_t)zb * sC_b + (size_t)zh * sC_h;
#pragma unroll
        for (int i = 0; i < 4; i++)
#pragma unroll
            for (int j = 0; j < 4; j++)
#pragma unroll
                for (int p = 0; p < 4; p++)
                    C[(size_t)(row0 + i * 16 + p) * ldc + (col0 + j * 16)] = acc[i][j][p];
    } else if (MODE == 1) {
        bf16* C = (bf16*)Cp + (size_t)zb * sC_b + (size_t)zh * sC_h;
#pragma unroll
        for (int i = 0; i < 4; i++)
#pragma unroll
            for (int j = 0; j < 4; j++)
#pragma unroll
                for (int p = 0; p < 4; p++)
                    C[(size_t)(row0 + i * 16 + p) * ldc + (col0 + j * 16)] =
                        __float2bfloat16(acc[i][j][p]);
    } else {  // MODE 3: scores + legal bias; h = zh, batch = bbase + zb
        float* C = (float*)Cp + (size_t)zb * sC_b + (size_t)zh * sC_h;
        const int h = zh;
        const int bbatch = bbase + zb;
        const float bsc = bias_sc[h];
        if (h == 0) {  // causal triu(k=1)
#pragma unroll
            for (int i = 0; i < 4; i++)
#pragma unroll
                for (int j = 0; j < 4; j++)
#pragma unroll
                    for (int p = 0; p < 4; p++) {
                        const int rr = row0 + i * 16 + p, c = col0 + j * 16;
                        C[(size_t)rr * ldc + c] = acc[i][j][p] + ((c > rr) ? bsc : 0.0f);
                    }
        } else if (h == 2) {  // proximity
#pragma unroll
            for (int i = 0; i < 4; i++)
#pragma unroll
                for (int j = 0; j < 4; j++)
#pragma unroll
                    for (int p = 0; p < 4; p++) {
                        const int rr = row0 + i * 16 + p, c = col0 + j * 16;
                        int d = c - rr; d = d < 0 ? -d : d;
                        C[(size_t)rr * ldc + c] =
                            acc[i][j][p] + bsc * expf(-(float)d * (1.0f / 2048.0f));
                    }
        } else {  // h==1 intent (> mean) / h==3 violation (> 0.5), exact fp64 compare
            const double* src = (h == 1) ? mag1d : v3d;
            const double thr = (h == 1) ? meand[0] : 0.5;
            double rv[16], cv[4];
#pragma unroll
            for (int i = 0; i < 4; i++)
#pragma unroll
                for (int p = 0; p < 4; p++)
                    rv[i * 4 + p] = src[(size_t)bbatch * S_ + row0 + i * 16 + p];
#pragma unroll
            for (int j = 0; j < 4; j++)
                cv[j] = src[(size_t)bbatch * S_ + col0 + j * 16];
#pragma unroll
            for (int i = 0; i < 4; i++)
#pragma unroll
                for (int j = 0; j < 4; j++)
#pragma unroll
                    for (int p = 0; p < 4; p++) {
                        const int rr = row0 + i * 16 + p, c = col0 + j * 16;
                        C[(size_t)rr * ldc + c] =
                            acc[i][j][p] + ((rv[i * 4 + p] * cv[j] > thr) ? bsc : 0.0f);
                    }
        }
    }
}

// fp32 -> bf16 (optionally scaled), 4 elems/thread
__global__ __launch_bounds__(256) void cvt_bf16(const float* __restrict__ in,
                                                bf16* __restrict__ out, int n,
                                                float scale) {
    const size_t i0 = ((size_t)blockIdx.x * 256 + threadIdx.x) * 4;
    if (i0 + 3 < (size_t)n) {
        const float4 v = *(const float4*)(in + i0);
        out[i0 + 0] = __float2bfloat16(v.x * scale);
        out[i0 + 1] = __float2bfloat16(v.y * scale);
        out[i0 + 2] = __float2bfloat16(v.z * scale);
        out[i0 + 3] = __float2bfloat16(v.w * scale);
    }
}

// Vraw [H, B*S, hd] -> Vt [H, B, hd, S]  (64x64 bf16 LDS tile transpose)
__global__ __launch_bounds__(256) void transpose_v(const bf16* __restrict__ in,
                                                   bf16* __restrict__ out) {
    const int h = blockIdx.z / B_, b = blockIdx.z % B_;
    const int e0 = blockIdx.x * 64, s0 = blockIdx.y * 64;
    __shared__ short t[64][66];
    const int tid = threadIdx.x;
    const int rr = tid >> 2;            // 0..63
    const int cc = (tid & 3) << 4;      // 0,16,32,48
    const bf16* ip = in + (((size_t)h * B_ * S_) + (size_t)b * S_ + s0) * HD_ + e0;
    const s16x8 v0 = *(const s16x8*)(ip + (size_t)rr * HD_ + cc);
    const s16x8 v1 = *(const s16x8*)(ip + (size_t)rr * HD_ + cc + 8);
#pragma unroll
    for (int i = 0; i < 8; i++) {
        t[rr][cc + i] = v0[i];
        t[rr][cc + 8 + i] = v1[i];
    }
    __syncthreads();
    bf16* op = out + (((size_t)h * B_ + b) * HD_ + e0 + rr) * S_ + s0 + cc;
    s16x8 o0, o1;
#pragma unroll
    for (int i = 0; i < 8; i++) {
        o0[i] = t[cc + i][rr];
        o1[i] = t[cc + 8 + i][rr];
    }
    *(s16x8*)op = o0;
    *(s16x8*)(op + 8) = o1;
}

// mag1[b,s] = ||emb[b,s,256:512]|| (fp64), v3[b,s] = emb[b,s,1023]
__global__ __launch_bounds__(256) void prep_kernel(const float* __restrict__ emb,
                                                   double* __restrict__ mag1d,
                                                   double* __restrict__ v3d) {
    const long row = blockIdx.x;
    const int tid = threadIdx.x;
    const float x = emb[row * D_ + 256 + tid];
    __shared__ double red[256];
    red[tid] = (double)x * (double)x;
    __syncthreads();
    for (int off = 128; off > 0; off >>= 1) {
        if (tid < off) red[tid] += red[tid + off];
        __syncthreads();
    }
    if (tid == 0) {
        mag1d[row] = sqrt(red[0]);
        v3d[row] = (double)emb[row * D_ + 1023];
    }
}

__global__ __launch_bounds__(256) void mean_kernel(const double* __restrict__ mag1d,
                                                   double* __restrict__ meand) {
    const int tid = threadIdx.x;
    __shared__ double red[256];
    double acc = 0.0;
    for (int b = 0; b < B_; b++) {
        double ss = 0.0;
        for (int i = tid; i < S_; i += 256) ss += mag1d[(long)b * S_ + i];
        __syncthreads();
        red[tid] = ss;
        __syncthreads();
        for (int off = 128; off > 0; off >>= 1) {
            if (tid < off) red[tid] += red[tid + off];
            __syncthreads();
        }
        if (tid == 0) {
            const double rb = red[0] / (double)S_;
            acc += rb * rb;
        }
        __syncthreads();
    }
    if (tid == 0) meand[0] = acc / (double)B_;
}

// Per row s (one b): softmax over all 4 heads (fp32, same op order as R2),
// write P bf16 (layout via p_h/p_row strides), accumulate avgw + rowsum.
__global__ __launch_bounds__(256) void softmax_fused(
    const float* __restrict__ scores, bf16* __restrict__ P, long p_h, int p_row,
    float* __restrict__ avgw, float* __restrict__ rowsum) {
    const int s = blockIdx.x, tid = threadIdx.x;
    __shared__ float red[256];
    float wacc[8] = {0, 0, 0, 0, 0, 0, 0, 0};
    for (int h = 0; h < H_; h++) {
        const float* rp = scores + ((size_t)h * S_ + s) * S_;
        bf16* pp = P + (size_t)h * p_h + (size_t)s * p_row;
        float v[8];
        float m = -1e30f;
#pragma unroll
        for (int i = 0; i < 8; i++) {
            v[i] = rp[tid + 256 * i];
            m = fmaxf(m, v[i]);
        }
        red[tid] = m;
        __syncthreads();
        for (int off = 128; off > 0; off >>= 1) {
            if (tid < off) red[tid] = fmaxf(red[tid], red[tid + off]);
            __syncthreads();
        }
        m = red[0];
        __syncthreads();
        float sum = 0.0f;
#pragma unroll
        for (int i = 0; i < 8; i++) {
            v[i] = expf(v[i] - m);
            sum += v[i];
        }
        red[tid] = sum;
        __syncthreads();
        for (int off = 128; off > 0; off >>= 1) {
            if (tid < off) red[tid] += red[tid + off];
            __syncthreads();
        }
        const float inv = 1.0f / red[0];
        __syncthreads();
#pragma unroll
        for (int i = 0; i < 8; i++) {
            const float wv = v[i] * inv;
            pp[tid + 256 * i] = __float2bfloat16(wv);
            wacc[i] += wv;
        }
    }
    float asum = 0.0f;
#pragma unroll
    for (int i = 0; i < 8; i++) {
        const float a = wacc[i] * 0.25f;
        avgw[(size_t)s * S_ + tid + 256 * i] = a;
        asum += a;
    }
    red[tid] = asum;
    __syncthreads();
    for (int off = 128; off > 0; off >>= 1) {
        if (tid < off) red[tid] += red[tid + off];
        __syncthreads();
    }
    if (tid == 0) rowsum[s] = red[0];
}

// y = proj + Wo_b + emb; LayerNorm(y) in place
__global__ __launch_bounds__(256) void ln_kernel(float* __restrict__ out,
                                                 const float* __restrict__ emb,
                                                 const float* __restrict__ wob,
                                                 const float* __restrict__ g,
                                                 const float* __restrict__ beta) {
    const long row = blockIdx.x;
    float* o = out + row * D_;
    const float* e = emb + row * D_;
    const int tid = threadIdx.x;
    __shared__ float red[256];
    float v[4];
    float sum = 0.0f;
#pragma unroll
    for (int i = 0; i < 4; i++) {
        const int c = tid + 256 * i;
        v[i] = o[c] + wob[c] + e[c];
        sum += v[i];
    }
    red[tid] = sum;
    __syncthreads();
    for (int off = 128; off > 0; off >>= 1) {
        if (tid < off) red[tid] += red[tid + off];
        __syncthreads();
    }
    const float mu = red[0] * (1.0f / 1024.0f);
    __syncthreads();
    float vs = 0.0f;
#pragma unroll
    for (int i = 0; i < 4; i++) {
        const float d = v[i] - mu;
        vs += d * d;
    }
    red[tid] = vs;
    __syncthreads();
    for (int off = 128; off > 0; off >>= 1) {
        if (tid < off) red[tid] += red[tid + off];
        __syncthreads();
    }
    const float var = red[0] * (1.0f / 1024.0f);
    const float inv = 1.0f / sqrtf(var + 1e-5f);
#pragma unroll
    for (int i = 0; i < 4; i++) {
        const int c = tid + 256 * i;
        o[c] = (v[i] - mu) * inv * g[c] + beta[c];
    }
}

__global__ __launch_bounds__(256) void guilt_kernel(const float* __restrict__ rowsum,
                                                    float* __restrict__ guilt) {
    const int b = blockIdx.x, tid = threadIdx.x;
    const float* r = rowsum + (long)b * S_;
    float* gq = guilt + (long)b * S_;
    __shared__ float red[256];
    float v[8];
    float m = -1e30f;
#pragma unroll
    for (int i = 0; i < 8; i++) {
        v[i] = r[tid + 256 * i];
        m = fmaxf(m, v[i]);
    }
    red[tid] = m;
    __syncthreads();
    for (int off = 128; off > 0; off >>= 1) {
        if (tid < off) red[tid] = fmaxf(red[tid], red[tid + off]);
        __syncthreads();
    }
    m = red[0];
    __syncthreads();
    float sum = 0.0f;
#pragma unroll
    for (int i = 0; i < 8; i++) {
        v[i] = expf(v[i] - m);
        sum += v[i];
    }
    red[tid] = sum;
    __syncthreads();
    for (int off = 128; off > 0; off >>= 1) {
        if (tid < off) red[tid] += red[tid + off];
        __syncthreads();
    }
    const float inv = 1.0f / red[0];
#pragma unroll
    for (int i = 0; i < 8; i++) gq[tid + 256 * i] = v[i] * inv;
}

extern "C" void kernel_launch(void* const* d_in, const int* in_sizes, int n_in,
                              void* d_out, int out_size, void* d_ws, size_t ws_size,
                              hipStream_t stream) {
    const float* emb = (const float*)d_in[0];
    const float* Wq = (const float*)d_in[1];
    const float* Wk = (const float*)d_in[2];
    const float* Wv = (const float*)d_in[3];
    const float* bias_sc = (const float*)d_in[4];
    const float* Wo_w = (const float*)d_in[5];
    const float* Wo_b = (const float*)d_in[6];
    const float* ln_g = (const float*)d_in[7];
    const float* ln_bt = (const float*)d_in[8];

    char* ws = (char*)d_ws;
    size_t off = 0;
    auto alloc = [&](size_t bytes) {
        size_t o = off;
        off = (off + bytes + 255) & ~(size_t)255;
        return o;
    };
    bf16* embb = (bf16*)(ws + alloc((size_t)B_ * S_ * D_ * 2));
    bf16* concat = embb;  // alias: embb dead after QKV GEMMs, concat written later
    bf16* Qm = (bf16*)(ws + alloc((size_t)H_ * B_ * S_ * HD_ * 2));  // [H,B*S,hd]
    bf16* Km = (bf16*)(ws + alloc((size_t)H_ * B_ * S_ * HD_ * 2));
    bf16* Vtb = (bf16*)(ws + alloc((size_t)H_ * B_ * HD_ * S_ * 2)); // [H,B,hd,S]
    bf16* Wqb = (bf16*)(ws + alloc((size_t)H_ * HD_ * HD_ * 2));
    bf16* Wkb = (bf16*)(ws + alloc((size_t)H_ * HD_ * HD_ * 2));
    bf16* Wvb = (bf16*)(ws + alloc((size_t)H_ * HD_ * HD_ * 2));
    bf16* Wob = (bf16*)(ws + alloc((size_t)D_ * D_ * 2));
    double* mag1d = (double*)(ws + alloc((size_t)B_ * S_ * 8));
    double* v3d = (double*)(ws + alloc((size_t)B_ * S_ * 8));
    double* meand = (double*)(ws + alloc(256));
    float* rowsum = (float*)(ws + alloc((size_t)B_ * S_ * 4));
    float* scores = (float*)(ws + alloc((size_t)H_ * S_ * S_ * 4));  // one b
    bf16* Vraw = (bf16*)scores;  // alias: Vraw consumed (transposed) before scores b=0
    bf16* P = (bf16*)(ws + off);  // Path A only: [B,H,S,S] bf16
    const size_t need_batched = off + (size_t)B_ * H_ * S_ * S_ * 2;
    const bool batched = ws_size >= need_batched;

    float* outp = (float*)d_out;
    float* avgw = outp + (size_t)B_ * S_ * D_;
    float* guilt = avgw + (size_t)B_ * S_ * S_;

    // casts (Q-scale 1/16 folded into Wq)
    cvt_bf16<<<(B_ * S_ * D_) / 1024, 256, 0, stream>>>(emb, embb, B_ * S_ * D_, 1.0f);
    cvt_bf16<<<(H_ * HD_ * HD_) / 1024, 256, 0, stream>>>(Wq, Wqb, H_ * HD_ * HD_, 0.0625f);
    cvt_bf16<<<(H_ * HD_ * HD_) / 1024, 256, 0, stream>>>(Wk, Wkb, H_ * HD_ * HD_, 1.0f);
    cvt_bf16<<<(H_ * HD_ * HD_) / 1024, 256, 0, stream>>>(Wv, Wvb, H_ * HD_ * HD_, 1.0f);
    cvt_bf16<<<(D_ * D_) / 1024, 256, 0, stream>>>(Wo_w, Wob, D_ * D_, 1.0f);

    prep_kernel<<<B_ * S_, 256, 0, stream>>>(emb, mag1d, v3d);
    mean_kernel<<<1, 256, 0, stream>>>(mag1d, meand);

    // QKV projections: MFMA, M = B*S (=8192), N = hd, K = hd, z = head
    {
        const dim3 g(HD_ / 128, (B_ * S_) / 128, H_);
        const long sQ = (long)B_ * S_ * HD_;
        mfma_nt<1><<<g, 256, 0, stream>>>(HD_, embb, D_, 0, HD_,
                                          Wqb, HD_, 0, (long)HD_ * HD_,
                                          Qm, HD_, 0, sQ, H_, 0,
                                          nullptr, nullptr, nullptr, nullptr);
        mfma_nt<1><<<g, 256, 0, stream>>>(HD_, embb, D_, 0, HD_,
                                          Wkb, HD_, 0, (long)HD_ * HD_,
                                          Km, HD_, 0, sQ, H_, 0,
                                          nullptr, nullptr, nullptr, nullptr);
        mfma_nt<1><<<g, 256, 0, stream>>>(HD_, embb, D_, 0, HD_,
                                          Wvb, HD_, 0, (long)HD_ * HD_,
                                          Vraw, HD_, 0, sQ, H_, 0,
                                          nullptr, nullptr, nullptr, nullptr);
    }
    transpose_v<<<dim3(HD_ / 64, S_ / 64, H_ * B_), 256, 0, stream>>>(Vraw, Vtb);

    for (int b = 0; b < B_; b++) {
        // scores[h,s,t] = Q.K^T + bias  (fp32 out, per-b buffer stays L3-warm)
        mfma_nt<3><<<dim3(S_ / 128, S_ / 128, H_), 256, 0, stream>>>(
            HD_,
            Qm + (size_t)b * S_ * HD_, HD_, 0, (long)B_ * S_ * HD_,
            Km + (size_t)b * S_ * HD_, HD_, 0, (long)B_ * S_ * HD_,
            scores, S_, 0, (long)S_ * S_,
            H_, b, mag1d, v3d, meand, bias_sc);
        if (batched) {
            softmax_fused<<<S_, 256, 0, stream>>>(
                scores, P + (size_t)b * H_ * S_ * S_, (long)S_ * S_, S_,
                avgw + (size_t)b * S_ * S_, rowsum + (size_t)b * S_);
        } else {
            // P bf16 in place over the fp32 scores rows (row stride 2S)
            softmax_fused<<<S_, 256, 0, stream>>>(
                scores, (bf16*)scores, 2L * S_ * S_, 2 * S_,
                avgw + (size_t)b * S_ * S_, rowsum + (size_t)b * S_);
            mfma_nt<1><<<dim3(HD_ / 128, S_ / 128, H_), 256, 0, stream>>>(
                S_,
                (const bf16*)scores, 2 * S_, 0, 2L * S_ * S_,
                Vtb + (size_t)b * HD_ * S_, S_, 0, (long)B_ * HD_ * S_,
                concat + (size_t)b * S_ * D_, D_, 0, HD_,
                H_, 0, nullptr, nullptr, nullptr, nullptr);
        }
    }
    if (batched) {
        // attended = P.V for all (b,h) in one dispatch (512 blocks)
        mfma_nt<1><<<dim3(HD_ / 128, S_ / 128, B_ * H_), 256, 0, stream>>>(
            S_,
            P, S_, (long)H_ * S_ * S_, (long)S_ * S_,
            Vtb, S_, (long)HD_ * S_, (long)B_ * HD_ * S_,
            concat, D_, (long)S_ * D_, HD_,
            H_, 0, nullptr, nullptr, nullptr, nullptr);
    }

    // out = concat @ Wo^T (MFMA, bf16 Wo)
    mfma_nt<0><<<dim3(D_ / 128, (B_ * S_) / 128, 1), 256, 0, stream>>>(
        D_, concat, D_, 0, 0, Wob, D_, 0, 0, outp, D_, 0, 0,
        1, 0, nullptr, nullptr, nullptr, nullptr);

    ln_kernel<<<B_ * S_, 256, 0, stream>>>(outp, emb, Wo_b, ln_g, ln_bt);
    guilt_kernel<<<B_, 256, 0, stream>>>(rowsum, guilt);
}